// Round 8
// baseline (304.728 us; speedup 1.0000x reference)
//
#include <hip/hip_runtime.h>
#include <hip/hip_bf16.h>

#define DM 2048
#define NH 4
#define DI 64
#define TQS 4096
#define TKS 4096
#define BB 2

typedef __attribute__((ext_vector_type(4))) float f32x4;
typedef __attribute__((ext_vector_type(8))) short bf16x8;

typedef __attribute__((address_space(1))) const void gvoid;
typedef __attribute__((address_space(3))) void lvoid;

__device__ __forceinline__ short f2bf(float f) {
  __hip_bfloat16 h = __float2bfloat16(f);
  return __builtin_bit_cast(short, h);
}

__device__ __forceinline__ bf16x8 cvt8(f32x4 a, f32x4 b) {
  bf16x8 r;
  r[0] = f2bf(a[0]); r[1] = f2bf(a[1]); r[2] = f2bf(a[2]); r[3] = f2bf(a[3]);
  r[4] = f2bf(b[0]); r[5] = f2bf(b[1]); r[6] = f2bf(b[2]); r[7] = f2bf(b[3]);
  return r;
}

// Packed-B layout for proj (round-6 win): Pq[jt][k64][ks][lane][8] — each
// B-load instruction reads 64 lanes x 16 B CONTIGUOUS (16 lines/inst).
__global__ __launch_bounds__(256) void pack_qw(const float* __restrict__ Wq,
                                               const float* __restrict__ Ww,
                                               short* __restrict__ P) {
  int idx = blockIdx.x * 256 + threadIdx.x;  // total 20*32*2*64*8
  int j = idx & 7;
  int lane = (idx >> 3) & 63;
  int ks = (idx >> 9) & 1;
  int k64 = (idx >> 10) & 31;
  int jt = idx >> 15;
  int n = jt * 16 + (lane & 15);
  int k = k64 * 64 + ks * 32 + (lane >> 4) * 8 + j;
  float v = 0.f;
  if (n < 256) v = Wq[(size_t)k * 256 + n];
  else if (n < 260) v = Ww[(size_t)k * 4 + (n - 256)];
  P[idx] = f2bf(v);
}

__global__ __launch_bounds__(256) void pack_k(const float* __restrict__ Wk,
                                              short* __restrict__ P) {
  int idx = blockIdx.x * 256 + threadIdx.x;  // total 4*32*2*64*8
  int j = idx & 7;
  int lane = (idx >> 3) & 63;
  int ks = (idx >> 9) & 1;
  int k64 = (idx >> 10) & 31;
  int jt = idx >> 15;
  int n = jt * 16 + (lane & 15);
  int k = k64 * 64 + ks * 32 + (lane >> 4) * 8 + j;
  P[idx] = f2bf(Wk[(size_t)k * 64 + n]);
}

// proj v9 = r7 structure (4-deep ring + packed B), epilogue now writes
// outputs in SCORE's MFMA-fragment order (round-7 lesson: score's q loads
// were 64 lines/inst at 512-B lane stride — the same pathology r6 fixed for
// proj's B. Producer-side repack is free: same store count, new addresses).
//   qbp[T][h][ks][lane][8]: element = q_I[token T*16+(lane&15)]
//                                       [feat h*64+ks*32+(lane>>4)*8+j]
//   kbp[T][ks][lane][8]  : same with 64 feats, no h
//   wI2[h][8192]         : planar per-head (score reads f32x4 per 4 rows)
template <int NJ, bool QP>
__device__ __forceinline__ void proj_body(const float* __restrict__ X,
                                          const short* __restrict__ P,
                                          short* __restrict__ O,
                                          float* __restrict__ wI, int blk,
                                          float* As /* [4][2048] LDS */) {
  const int tid = threadIdx.x;
  const int wave = tid >> 6, lane = tid & 63;
  const int l15 = lane & 15, quad = lane >> 4;
  const int m0 = blk * 32;
  constexpr int NB = NJ * 2;  // B register loads per iteration

  int jt[NJ];
#pragma unroll
  for (int jj = 0; jj < NJ; ++jj) jt[jj] = QP ? (jj < 4 ? jj * 4 + wave : 16 + wave) : wave;

  const short* wb[NJ];
#pragma unroll
  for (int jj = 0; jj < NJ; ++jj) wb[jj] = P + (size_t)jt[jj] * 32768 + lane * 8;

  // Stage: thread t fills linear LDS slots {t*16, 4096+t*16} (rows srow,
  // srow+16) from pre-swizzled global chunk (t&15)^srow (rule #21).
  const int srow = tid >> 4;
  const int schunk = (tid & 15) ^ srow;
  const float* s0 = X + (size_t)(m0 + srow) * DM + schunk * 4;
  const float* s1 = X + (size_t)(m0 + 16 + srow) * DM + schunk * 4;
  const int d0 = tid * 16, d1 = 4096 + tid * 16;
  char* lb = (char*)As;

  // Prologue: S(0),S(1),S(2), then B(0); drain own S(0) share; barrier.
#pragma unroll
  for (int s = 0; s < 3; ++s) {
    __builtin_amdgcn_global_load_lds((gvoid*)(s0 + s * 64), (lvoid*)(lb + s * 8192 + d0), 16, 0, 0);
    __builtin_amdgcn_global_load_lds((gvoid*)(s1 + s * 64), (lvoid*)(lb + s * 8192 + d1), 16, 0, 0);
  }
  bf16x8 bb[2][NJ][2];
#pragma unroll
  for (int jj = 0; jj < NJ; ++jj)
#pragma unroll
    for (int ks = 0; ks < 2; ++ks)
      bb[0][jj][ks] = *(const bf16x8*)(wb[jj] + ks * 512);
  __builtin_amdgcn_sched_barrier(0);
  asm volatile("s_waitcnt vmcnt(%0)" ::"i"(4 + NB));
  __builtin_amdgcn_sched_barrier(0);
  __builtin_amdgcn_s_barrier();

  const f32x4 z = {0.f, 0.f, 0.f, 0.f};
  f32x4 acc[NJ][2];
#pragma unroll
  for (int jj = 0; jj < NJ; ++jj)
#pragma unroll
    for (int i = 0; i < 2; ++i) acc[jj][i] = z;

  auto loadB = [&](int t1, int bbi) {
#pragma unroll
    for (int jj = 0; jj < NJ; ++jj)
#pragma unroll
      for (int ks = 0; ks < 2; ++ks)
        bb[bbi][jj][ks] = *(const bf16x8*)(wb[jj] + t1 * 1024 + ks * 512);
  };
  auto stage = [&](int t3) {
    char* l = lb + (t3 & 3) * 8192;
    __builtin_amdgcn_global_load_lds((gvoid*)(s0 + t3 * 64), (lvoid*)(l + d0), 16, 0, 0);
    __builtin_amdgcn_global_load_lds((gvoid*)(s1 + t3 * 64), (lvoid*)(l + d1), 16, 0, 0);
  };
  auto compute = [&](int cur, int bbi) {
    const float* Ab = As + cur * 2048;
    bf16x8 abf[2][2];
#pragma unroll
    for (int i = 0; i < 2; ++i)
#pragma unroll
      for (int ks = 0; ks < 2; ++ks) {
        const int rb = (i * 16 + l15) * 64;
        const int cg = ks * 8 + quad * 2;
        f32x4 a0 = *(const f32x4*)(Ab + rb + ((cg ^ l15) << 2));
        f32x4 a1 = *(const f32x4*)(Ab + rb + (((cg + 1) ^ l15) << 2));
        abf[i][ks] = cvt8(a0, a1);
      }
#pragma unroll
    for (int jj = 0; jj < NJ; ++jj)
#pragma unroll
      for (int i = 0; i < 2; ++i)
#pragma unroll
        for (int ks = 0; ks < 2; ++ks)
          acc[jj][i] = __builtin_amdgcn_mfma_f32_16x16x32_bf16(abf[i][ks], bb[bbi][jj][ks],
                                                               acc[jj][i], 0, 0, 0);
  };

#pragma unroll 4
  for (int t = 0; t < 28; ++t) {
    loadB(t + 1, (t + 1) & 1);           // B first: its wait never drains S(t+2,3)
    __builtin_amdgcn_sched_barrier(0);
    stage(t + 3);                        // 3 stages in flight, never drained
    __builtin_amdgcn_sched_barrier(0);
    compute(t & 3, t & 1);
    __builtin_amdgcn_sched_barrier(0);
    __builtin_amdgcn_s_barrier();        // raw: no waitcnt drain
  }
  // Peeled tail, static ring/parity indices (rule #20).
  loadB(29, 1);
  __builtin_amdgcn_sched_barrier(0);
  stage(31);
  __builtin_amdgcn_sched_barrier(0);
  compute(0, 0);  // t=28
  __builtin_amdgcn_sched_barrier(0);
  __builtin_amdgcn_s_barrier();

  loadB(30, 0);
  __builtin_amdgcn_sched_barrier(0);
  compute(1, 1);  // t=29
  __builtin_amdgcn_sched_barrier(0);
  __builtin_amdgcn_s_barrier();

  loadB(31, 1);
  __builtin_amdgcn_sched_barrier(0);
  compute(2, 0);  // t=30
  __builtin_amdgcn_sched_barrier(0);
  __builtin_amdgcn_s_barrier();

  compute(3, 1);  // t=31

  // Epilogue: C row = quad*4 + r (token), col = l15 (feature within tile).
  // Write in score-fragment order.
#pragma unroll
  for (int jj = 0; jj < NJ; ++jj) {
    if (QP && jt[jj] >= 16) {
      if (jt[jj] == 16 && l15 < 4) {  // Ww columns -> wI2[h][8192]
#pragma unroll
        for (int i = 0; i < 2; ++i)
#pragma unroll
          for (int r = 0; r < 4; ++r)
            wI[(size_t)l15 * 8192 + m0 + i * 16 + quad * 4 + r] = acc[jj][i][r];
      }
    } else {
      const int n = jt[jj] * 16 + l15;            // feature 0..255 (q) / 0..63 (k)
      const int h = n >> 6, ks = (n >> 5) & 1;
      const int n31 = n & 31;
      const int lh = n31 >> 3, j = n31 & 7;
      constexpr int NHH = QP ? 4 : 1;
#pragma unroll
      for (int i = 0; i < 2; ++i) {
        const size_t T = (size_t)blk * 2 + i;     // token/16
        short* ob = O + ((T * NHH + h) * 2 + ks) * 512 + j;
#pragma unroll
        for (int r = 0; r < 4; ++r)
          ob[(lh * 16 + quad * 4 + r) * 8] = f2bf(acc[jj][i][r]);
      }
    }
  }
}

__global__ __launch_bounds__(256, 2) void proj_fused(const float* __restrict__ xq,
                                                     const float* __restrict__ xk,
                                                     const short* __restrict__ Pq,
                                                     const short* __restrict__ Pk,
                                                     short* __restrict__ qbp,
                                                     short* __restrict__ kbp,
                                                     float* __restrict__ wI2) {
  __shared__ __align__(16) float As[4][2048];  // 32 KB: 4-deep ring of [32r][64 f32]
  if (blockIdx.x < 256)
    proj_body<5, true>(xq, Pq, qbp, wI2, blockIdx.x, &As[0][0]);
  else
    proj_body<1, false>(xk, Pk, kbp, nullptr, blockIdx.x - 256, &As[0][0]);
}

// out[b][q][k] = sum_h wI[b,q,h] * relu(q_I[b,q,h,:] . k_I[b,k,:])
// 128x128 tile/block, 4 waves of 64x64. All operand loads now contiguous
// 1-KB fragment reads (16 lines/inst; was 64 for q); wv via f32x4.
__global__ __launch_bounds__(256, 2) void score_kernel(const short* __restrict__ qbp,
                                                       const short* __restrict__ kbp,
                                                       const float* __restrict__ wI2,
                                                       float* __restrict__ out) {
  const int b = blockIdx.z;
  const int qt = blockIdx.y;
  const int kt = blockIdx.x;
  const int tid = threadIdx.x;
  const int wave = tid >> 6, lane = tid & 63;
  const int wm = wave >> 1, wn = wave & 1;
  const int l15 = lane & 15, quad = lane >> 4;

  // Key fragments: token group Tk+j, reused across all heads.
  const int Tk = b * 256 + kt * 8 + wn * 4;
  bf16x8 bf[4][2];
#pragma unroll
  for (int j = 0; j < 4; ++j)
#pragma unroll
    for (int ks = 0; ks < 2; ++ks)
      bf[j][ks] = *(const bf16x8*)(kbp + ((size_t)(Tk + j) * 2 + ks) * 512 + lane * 8);

  const f32x4 z = {0.f, 0.f, 0.f, 0.f};
  f32x4 facc[4][4];
#pragma unroll
  for (int i = 0; i < 4; ++i)
#pragma unroll
    for (int j = 0; j < 4; ++j) facc[i][j] = z;

  const int Tq = b * 256 + qt * 8 + wm * 4;
  const short* qb0 = qbp + lane * 8;

  bf16x8 af[2][4][2];
#pragma unroll
  for (int i = 0; i < 4; ++i)
#pragma unroll
    for (int ks = 0; ks < 2; ++ks)
      af[0][i][ks] = *(const bf16x8*)(qb0 + (((size_t)(Tq + i) * 4 + 0) * 2 + ks) * 512);

#pragma unroll
  for (int h = 0; h < NH; ++h) {
    if (h < NH - 1) {  // prefetch next head's A fragments
#pragma unroll
      for (int i = 0; i < 4; ++i)
#pragma unroll
        for (int ks = 0; ks < 2; ++ks)
          af[(h + 1) & 1][i][ks] =
              *(const bf16x8*)(qb0 + (((size_t)(Tq + i) * 4 + (h + 1)) * 2 + ks) * 512);
    }

    f32x4 acc[4][4];
#pragma unroll
    for (int i = 0; i < 4; ++i)
#pragma unroll
      for (int j = 0; j < 4; ++j) acc[i][j] = z;

#pragma unroll
    for (int ks = 0; ks < 2; ++ks)
#pragma unroll
      for (int i = 0; i < 4; ++i)
#pragma unroll
        for (int j = 0; j < 4; ++j)
          acc[i][j] = __builtin_amdgcn_mfma_f32_16x16x32_bf16(
              af[h & 1][i][ks], bf[j][ks], acc[i][j], 0, 0, 0);

    const float* wb2 = wI2 + (size_t)h * 8192 + b * 4096 + qt * 128 + wm * 64 + quad * 4;
#pragma unroll
    for (int i = 0; i < 4; ++i) {
      const f32x4 wv = *(const f32x4*)(wb2 + i * 16);
#pragma unroll
      for (int j = 0; j < 4; ++j)
#pragma unroll
        for (int r = 0; r < 4; ++r)
          facc[i][j][r] += wv[r] * fmaxf(acc[i][j][r], 0.f);
    }
  }

  float* obase = out + (size_t)b * TQS * TKS +
                 (size_t)(qt * 128 + wm * 64 + quad * 4) * TKS + kt * 128 + wn * 64 + l15;
#pragma unroll
  for (int i = 0; i < 4; ++i)
#pragma unroll
    for (int r = 0; r < 4; ++r)
#pragma unroll
      for (int j = 0; j < 4; ++j)
        __builtin_nontemporal_store(facc[i][j][r],
                                    &obase[(size_t)(i * 16 + r) * TKS + j * 16]);
}

extern "C" void kernel_launch(void* const* d_in, const int* in_sizes, int n_in,
                              void* d_out, int out_size, void* d_ws, size_t ws_size,
                              hipStream_t stream) {
  const float* x_q = (const float*)d_in[0];  // [2,4096,2048]
  const float* x_k = (const float*)d_in[1];  // [2,4096,2048]
  const float* Wq  = (const float*)d_in[2];  // [2048,256]
  const float* Ww  = (const float*)d_in[3];  // [2048,4]
  const float* Wk  = (const float*)d_in[4];  // [2048,64]
  float* out = (float*)d_out;                // [2,4096,4096]

  char* ws = (char*)d_ws;
  short* qbp = (short*)(ws);                               // 512*4*2*512 bf16 = 4 MB
  short* kbp = (short*)(ws + (4u << 20));                  // 512*2*512 bf16 = 1 MB
  float* wI2 = (float*)(ws + (5u << 20));                  // 4*8192 f32 = 128 KB
  short* Pq  = (short*)(ws + (5u << 20) + (128u << 10));   // 20*32768 bf16 = 1.25 MB
  short* Pk  = (short*)(ws + (7u << 20));                  // 4*32768 bf16 = 256 KB

  pack_qw<<<(20 * 32768) / 256, 256, 0, stream>>>(Wq, Ww, Pq);
  pack_k<<<(4 * 32768) / 256, 256, 0, stream>>>(Wk, Pk);

  // Fused projections: blocks 0-255 -> q (+w), 256-511 -> k. x read exactly once.
  proj_fused<<<512, 256, 0, stream>>>(x_q, x_k, Pq, Pk, qbp, kbp, wI2);

  score_kernel<<<dim3(TKS / 128, TQS / 128, BB), 256, 0, stream>>>(qbp, kbp, wI2, out);
}